// Round 21
// baseline (92.353 us; speedup 1.0000x reference)
//
#include <hip/hip_runtime.h>
#include <math.h>

#define NB 2
#define NC 128
#define NN 4096
#define C2L 2.88539008177792681472f   // 2*log2(e)

typedef __attribute__((ext_vector_type(8))) short short8;
typedef __attribute__((ext_vector_type(4))) float f32x4;

// g_Tb: bf16 [n][k], UNSWIZZLED. g_Sb: bf16 [n][k], 16B-chunk c at c^(n&7).
__device__ unsigned short g_Tb[NB][NN][NC];
__device__ unsigned short g_Sb[NB][NN][NC];
__device__ float g_tsqr[NB][NN];
__device__ float g_ssqr[NB][NN];
__device__ float g_rowS[NB][NN];    // -(2*log2e/(rowmin+eps))
__device__ float g_rowLZ[NB][NN];   // log2(ZB)
__device__ float g_rowE[NB][NN];    // mA
__device__ float g_colS[NB][NN];
__device__ float g_colLZ[NB][NN];
__device__ float g_colE[NB][NN];
__device__ float g_colpart[NB][128][NN];  // slot = st*4 + wave, exclusive
__device__ float g_rowpart[NB][16][NN];   // slot = col-group pn (0-7), exclusive

#if __has_builtin(__builtin_amdgcn_exp2f)
__device__ __forceinline__ float fexp2(float x) { return __builtin_amdgcn_exp2f(x); }
#else
__device__ __forceinline__ float fexp2(float x) { return exp2f(x); }
#endif

#define GLL16(gsrc, ldst) \
  __builtin_amdgcn_global_load_lds((const __attribute__((address_space(1))) void*)(gsrc), \
                                   (__attribute__((address_space(3))) void*)(ldst), 16, 0, 0)

__device__ __forceinline__ unsigned f2bf(float f) {
    unsigned u = __float_as_uint(f);
    u += 0x7FFFu + ((u >> 16) & 1u);   // RNE
    return u >> 16;
}

// fp32 [k][n] -> bf16 [n][k]; S gets the chunk-XOR swizzle, T stays linear.
__global__ void __launch_bounds__(256) transpose_prep(const float* __restrict__ src,
                                                      const float* __restrict__ tgt) {
    __shared__ float ls[NC][68];
    __shared__ float redn[4][64];
    int bid = blockIdx.x;              // 2 mat x 2 b x 64 n-chunks = 256
    int mat = bid >> 7;                // 0 = S (src), 1 = T (tgt)
    int b   = (bid >> 6) & 1;
    int n0  = (bid & 63) << 6;
    int tid = threadIdx.x;
    const float* in = (mat ? tgt : src) + (size_t)b * NC * NN;
    unsigned short (*out)[NC] = mat ? g_Tb[b] : g_Sb[b];
    float* sq = mat ? g_tsqr[b] : g_ssqr[b];

    for (int idx = tid; idx < NC * 16; idx += 256) {
        int k = idx >> 4, c4 = (idx & 15) << 2;
        *(float4*)&ls[k][c4] = *(const float4*)(in + (size_t)k * NN + n0 + c4);
    }
    __syncthreads();
    {
        int n = tid & 63, c = tid >> 6;
        float psum = 0.f;
        for (int cc = c; cc < 16; cc += 4) {
            unsigned uo[4];
            #pragma unroll
            for (int e = 0; e < 4; ++e) {
                float v0 = ls[cc * 8 + 2 * e][n];
                float v1 = ls[cc * 8 + 2 * e + 1][n];
                psum = fmaf(v0, v0, psum);
                psum = fmaf(v1, v1, psum);
                uo[e] = f2bf(v0) | (f2bf(v1) << 16);
            }
            int swz = mat ? cc : (cc ^ (n & 7));
            *(uint4*)&out[n0 + n][swz * 8] = make_uint4(uo[0], uo[1], uo[2], uo[3]);
        }
        redn[c][n] = psum;
    }
    __syncthreads();
    if (tid < 64)
        sq[n0 + tid] = (redn[0][tid] + redn[1][tid]) + (redn[2][tid] + redn[3][tid]);
}

// Double-buffered panel sweep: block = 128 T-rows x 512 S-cols as 4 panels
// of 128 cols (32KB each, 2 LDS buffers). Stage p+1 issues BEFORE compute p
// -> stage hides under ~2us of MFMA/VALU; the plain __syncthreads drain at
// each panel boundary is covered (r4's failure was 600cy of cover; here 8x).
// Exposed stage = 32KB (half of r14). No atomics; exclusive partials.
template<int PASS>
__global__ void __launch_bounds__(256) sweep_kernel() {
    __shared__ unsigned short Sp[2][128 * NC];   // 2 x 32KB, swizzled images

    int bid = blockIdx.x;              // NB*32*8 = 512
    int b   = bid >> 8;
    int st  = (bid >> 3) & 31;
    int pn  = bid & 7;
    int i0  = st * 128;
    int j0  = pn * 512;
    int tid = threadIdx.x;
    int w = tid >> 6, lane = tid & 63, q = lane >> 4, x = lane & 15;
    int iw = i0 + w * 32;

    // stage panel 0 (32KB = 2048 chunks), linear LDS dest
    #pragma unroll
    for (int it = 0; it < 8; ++it) {
        int l = tid + it * 256;
        GLL16(&g_Sb[b][j0 + (l >> 4)][(l & 15) * 8], &Sp[0][l * 8]);
    }

    // A-fragments + row aux (overlap stage0)
    short8 af[2][4];
    #pragma unroll
    for (int m = 0; m < 2; ++m)
        #pragma unroll
        for (int kk = 0; kk < 4; ++kk)
            af[m][kk] = *(const short8*)&g_Tb[b][iw + m * 16 + x][(kk * 4 + q) * 8];

    float tq[8], rS[8], rC[8];
    #pragma unroll
    for (int m = 0; m < 2; ++m)
        #pragma unroll
        for (int v = 0; v < 4; ++v) {
            int row = iw + m * 16 + q * 4 + v;
            tq[m * 4 + v] = g_tsqr[b][row];
            rS[m * 4 + v] = (PASS >= 2) ? g_rowS[b][row] : 0.f;
            rC[m * 4 + v] = (PASS == 3) ? (C2L - g_rowLZ[b][row]) : 0.f;
        }

    // col aux for tile 0 (rolling prefetch-1 across all 8 tiles)
    float sqc[4], cSc[4], cCc[4], sqn[4], cSn[4], cCn[4];
    #pragma unroll
    for (int n = 0; n < 4; ++n) {
        int col = j0 + n * 16 + x;
        sqn[n] = g_ssqr[b][col];
        cSn[n] = (PASS >= 2) ? g_colS[b][col] : 0.f;
        cCn[n] = (PASS == 3) ? (C2L - g_colLZ[b][col]) : 0.f;
    }

    float rstate[8];
    #pragma unroll
    for (int e = 0; e < 8; ++e)
        rstate[e] = (PASS == 1) ? 3.0e38f : (PASS == 2 ? 0.f : -3.0e38f);

    __syncthreads();   // drain stage0 + af/aux (32KB exposed, half of r14)

    for (int p = 0; p < 4; ++p) {
        // issue stage p+1 into the other buffer -- hides under this panel's compute
        if (p < 3) {
            #pragma unroll
            for (int it = 0; it < 8; ++it) {
                int l = tid + it * 256;
                GLL16(&g_Sb[b][j0 + (p + 1) * 128 + (l >> 4)][(l & 15) * 8],
                      &Sp[(p + 1) & 1][l * 8]);
            }
        }

        #pragma unroll
        for (int jt = 0; jt < 2; ++jt) {
            int t = p * 2 + jt;
            #pragma unroll
            for (int n = 0; n < 4; ++n) { sqc[n] = sqn[n]; cSc[n] = cSn[n]; cCc[n] = cCn[n]; }
            if (t < 7) {
                #pragma unroll
                for (int n = 0; n < 4; ++n) {
                    int col = j0 + (t + 1) * 64 + n * 16 + x;
                    sqn[n] = g_ssqr[b][col];
                    if (PASS >= 2) cSn[n] = g_colS[b][col];
                    if (PASS == 3) cCn[n] = C2L - g_colLZ[b][col];
                }
            }

            f32x4 acc[2][4];
            #pragma unroll
            for (int m = 0; m < 2; ++m)
                #pragma unroll
                for (int n = 0; n < 4; ++n)
                    acc[m][n] = (f32x4){0.f, 0.f, 0.f, 0.f};

            #pragma unroll
            for (int kk = 0; kk < 4; ++kk) {
                short8 bf[4];
                #pragma unroll
                for (int n = 0; n < 4; ++n) {
                    int r  = jt * 64 + n * 16 + x;        // panel-local row
                    int ch = (kk * 4 + q) ^ (r & 7);
                    bf[n] = *(const short8*)&Sp[p & 1][r * NC + ch * 8];
                }
                #pragma unroll
                for (int m = 0; m < 2; ++m)
                    #pragma unroll
                    for (int n = 0; n < 4; ++n)
                        acc[m][n] = __builtin_amdgcn_mfma_f32_16x16x32_bf16(af[m][kk], bf[n], acc[m][n], 0, 0, 0);
            }

            float cstate[4];
            #pragma unroll
            for (int n = 0; n < 4; ++n)
                cstate[n] = (PASS == 1) ? 3.0e38f : (PASS == 2 ? 0.f : -3.0e38f);

            #pragma unroll
            for (int m = 0; m < 2; ++m)
                #pragma unroll
                for (int n = 0; n < 4; ++n)
                    #pragma unroll
                    for (int v = 0; v < 4; ++v) {
                        float dv = fmaxf(fmaf(-2.f, acc[m][n][v], tq[m * 4 + v] + sqc[n]), 0.f);
                        if (PASS == 1) {
                            rstate[m * 4 + v] = fminf(rstate[m * 4 + v], dv);
                            cstate[n]         = fminf(cstate[n], dv);
                        } else if (PASS == 2) {
                            rstate[m * 4 + v] += fexp2(fmaf(dv, rS[m * 4 + v], C2L));
                            cstate[n]         += fexp2(fmaf(dv, cSc[n], C2L));
                        } else {
                            rstate[m * 4 + v] = fmaxf(rstate[m * 4 + v], fmaf(dv, cSc[n], cCc[n]));
                            cstate[n]         = fmaxf(cstate[n], fmaf(dv, rS[m * 4 + v], rC[m * 4 + v]));
                        }
                    }

            // col partial: reduce over q-groups, exclusive store
            #pragma unroll
            for (int off = 16; off < 64; off <<= 1)
                #pragma unroll
                for (int n = 0; n < 4; ++n) {
                    float o = __shfl_xor(cstate[n], off);
                    cstate[n] = (PASS == 1) ? fminf(cstate[n], o)
                               : (PASS == 2) ? cstate[n] + o : fmaxf(cstate[n], o);
                }
            if (q == 0)
                #pragma unroll
                for (int n = 0; n < 4; ++n)
                    g_colpart[b][st * 4 + w][j0 + t * 64 + n * 16 + x] = cstate[n];
        }

        __syncthreads();   // drain stage p+1 (covered by compute) + buffer-reuse guard
    }

    // row partial: reduce over 16 x-lanes, exclusive store (slot = pn, 0-7)
    #pragma unroll
    for (int off = 1; off < 16; off <<= 1)
        #pragma unroll
        for (int e = 0; e < 8; ++e) {
            float o = __shfl_xor(rstate[e], off);
            rstate[e] = (PASS == 1) ? fminf(rstate[e], o)
                       : (PASS == 2) ? rstate[e] + o : fmaxf(rstate[e], o);
        }
    if (x == 0)
        #pragma unroll
        for (int e = 0; e < 8; ++e)
            g_rowpart[b][pn][iw + (e >> 2) * 16 + q * 4 + (e & 3)] = rstate[e];
}

// Wide reduce: 512 blocks (2/CU), 16 els/block x 16 lane-parts.
// Col: 8 slots/part (128 total); row: slots 0-7 only (parts 8-15 = identity).
template<int PASS>
__global__ void __launch_bounds__(256) reduce_kernel() {
    int bid = blockIdx.x;             // NB*256 = 512
    int b = bid >> 8, g = bid & 255;
    int tid = threadIdx.x;
    int el = g * 16 + (tid >> 4);
    int part = tid & 15;
    float ident = (PASS == 1) ? 3.0e38f : (PASS == 2 ? 0.f : -3.0e38f);

    float ca = ident;
    #pragma unroll
    for (int k = 0; k < 8; ++k) {
        float cv = g_colpart[b][part * 8 + k][el];
        if (PASS == 1) ca = fminf(ca, cv);
        else if (PASS == 2) ca += cv;
        else ca = fmaxf(ca, cv);
    }
    float ra = (part < 8) ? g_rowpart[b][part][el] : ident;

    #pragma unroll
    for (int off = 1; off < 16; off <<= 1) {
        float co = __shfl_xor(ca, off), ro = __shfl_xor(ra, off);
        if (PASS == 1) { ca = fminf(ca, co); ra = fminf(ra, ro); }
        else if (PASS == 2) { ca += co; ra += ro; }
        else { ca = fmaxf(ca, co); ra = fmaxf(ra, ro); }
    }
    if (part == 0) {
        if (PASS == 1) { g_colS[b][el] = -(C2L / (ca + 1e-5f)); g_rowS[b][el] = -(C2L / (ra + 1e-5f)); }
        if (PASS == 2) { g_colLZ[b][el] = log2f(ca);            g_rowLZ[b][el] = log2f(ra); }
        if (PASS == 3) { g_colE[b][el] = fexp2(ca);             g_rowE[b][el] = fexp2(ra); }
    }
}

__global__ void final_kernel(float* __restrict__ out) {
    int tid = threadIdx.x;
    float s[4] = {0.f, 0.f, 0.f, 0.f};
    for (int i = tid; i < NN; i += 256) {
        s[0] += g_rowE[0][i];
        s[1] += g_rowE[1][i];
        s[2] += g_colE[0][i];
        s[3] += g_colE[1][i];
    }
    __shared__ float red[4][4];
    int lane = tid & 63, w = tid >> 6;
    #pragma unroll
    for (int t = 0; t < 4; ++t) {
        float v = s[t];
        #pragma unroll
        for (int off = 32; off; off >>= 1) v += __shfl_down(v, off);
        if (lane == 0) red[t][w] = v;
    }
    __syncthreads();
    if (tid == 0) {
        float o = 0.f;
        #pragma unroll
        for (int t = 0; t < 4; ++t) {
            float S = red[t][0] + red[t][1] + red[t][2] + red[t][3];
            o += logf(S);
        }
        out[0] = logf((float)NN) - 0.25f * o;
    }
}

extern "C" void kernel_launch(void* const* d_in, const int* in_sizes, int n_in,
                              void* d_out, int out_size, void* d_ws, size_t ws_size,
                              hipStream_t stream) {
    const float* src = (const float*)d_in[0];
    const float* tgt = (const float*)d_in[1];
    (void)in_sizes; (void)n_in; (void)d_ws; (void)ws_size; (void)out_size;

    transpose_prep<<<256, 256, 0, stream>>>(src, tgt);
    sweep_kernel<1><<<512, 256, 0, stream>>>();
    reduce_kernel<1><<<512, 256, 0, stream>>>();
    sweep_kernel<2><<<512, 256, 0, stream>>>();
    reduce_kernel<2><<<512, 256, 0, stream>>>();
    sweep_kernel<3><<<512, 256, 0, stream>>>();
    reduce_kernel<3><<<512, 256, 0, stream>>>();
    final_kernel<<<1, 256, 0, stream>>>((float*)d_out);
}

// Round 22
// 89.614 us; speedup vs baseline: 1.0306x; 1.0306x over previous
//
#include <hip/hip_runtime.h>
#include <math.h>

#define NB 2
#define NC 128
#define NN 4096
#define C2L 2.88539008177792681472f   // 2*log2(e)

typedef __attribute__((ext_vector_type(8))) short short8;
typedef __attribute__((ext_vector_type(4))) float f32x4;

// g_Tb: bf16 [n][k], UNSWIZZLED (direct register fragment loads).
// g_Sb: bf16 [n][k], 16B-chunk c stored at c^(n&7) (LDS-bank swizzle baked in;
//       global_load_lds stages it linearly, ds_read applies the XOR).
__device__ unsigned short g_Tb[NB][NN][NC];
__device__ unsigned short g_Sb[NB][NN][NC];
__device__ float g_tsqr[NB][NN];
__device__ float g_ssqr[NB][NN];
__device__ float g_rowS[NB][NN];    // -(2*log2e/(rowmin+eps))
__device__ float g_rowLZ[NB][NN];   // log2(ZB)
__device__ float g_rowE[NB][NN];    // mA
__device__ float g_colS[NB][NN];
__device__ float g_colLZ[NB][NN];
__device__ float g_colE[NB][NN];
__device__ float g_colpart[NB][128][NN];  // slot = st*4 + wave, exclusive
__device__ float g_rowpart[NB][16][NN];   // slot = panel, exclusive

#if __has_builtin(__builtin_amdgcn_exp2f)
__device__ __forceinline__ float fexp2(float x) { return __builtin_amdgcn_exp2f(x); }
#else
__device__ __forceinline__ float fexp2(float x) { return exp2f(x); }
#endif

#define GLL16(gsrc, ldst) \
  __builtin_amdgcn_global_load_lds((const __attribute__((address_space(1))) void*)(gsrc), \
                                   (__attribute__((address_space(3))) void*)(ldst), 16, 0, 0)

__device__ __forceinline__ unsigned f2bf(float f) {
    unsigned u = __float_as_uint(f);
    u += 0x7FFFu + ((u >> 16) & 1u);   // RNE
    return u >> 16;
}

// fp32 [k][n] -> bf16 [n][k]; S gets the chunk-XOR swizzle, T stays linear.
// Norms computed on the ROW side while packing (no serial column phase).
__global__ void __launch_bounds__(256) transpose_prep(const float* __restrict__ src,
                                                      const float* __restrict__ tgt) {
    __shared__ float ls[NC][68];
    __shared__ float redn[4][64];
    int bid = blockIdx.x;              // 2 mat x 2 b x 64 n-chunks = 256
    int mat = bid >> 7;                // 0 = S (src), 1 = T (tgt)
    int b   = (bid >> 6) & 1;
    int n0  = (bid & 63) << 6;
    int tid = threadIdx.x;
    const float* in = (mat ? tgt : src) + (size_t)b * NC * NN;
    unsigned short (*out)[NC] = mat ? g_Tb[b] : g_Sb[b];
    float* sq = mat ? g_tsqr[b] : g_ssqr[b];

    for (int idx = tid; idx < NC * 16; idx += 256) {
        int k = idx >> 4, c4 = (idx & 15) << 2;
        *(float4*)&ls[k][c4] = *(const float4*)(in + (size_t)k * NN + n0 + c4);
    }
    __syncthreads();
    {
        int n = tid & 63, c = tid >> 6;
        float psum = 0.f;
        for (int cc = c; cc < 16; cc += 4) {
            unsigned uo[4];
            #pragma unroll
            for (int e = 0; e < 4; ++e) {
                float v0 = ls[cc * 8 + 2 * e][n];
                float v1 = ls[cc * 8 + 2 * e + 1][n];
                psum = fmaf(v0, v0, psum);
                psum = fmaf(v1, v1, psum);
                uo[e] = f2bf(v0) | (f2bf(v1) << 16);
            }
            int swz = mat ? cc : (cc ^ (n & 7));
            *(uint4*)&out[n0 + n][swz * 8] = make_uint4(uo[0], uo[1], uo[2], uo[3]);
        }
        redn[c][n] = psum;
    }
    __syncthreads();
    if (tid < 64)
        sq[n0 + tid] = (redn[0][tid] + redn[1][tid]) + (redn[2][tid] + redn[3][tid]);
}

// One-shot-staged sweep (r14, best verified): block = 128 T-rows (wave owns
// 32) x 256 S-cols; 64KB panel staged ONCE via global_load_lds (issued
// first). Main loop: pure LDS + MFMA + prefetched col aux. No atomics.
template<int PASS>
__global__ void __launch_bounds__(256) sweep_kernel() {
    __shared__ unsigned short Sp[256 * NC];   // 64KB, swizzled image

    int bid = blockIdx.x;              // NB*32*16 = 1024
    int b   = bid >> 9;
    int st  = (bid >> 4) & 31;
    int pn  = bid & 15;
    int i0  = st * 128;
    int j0  = pn * 256;
    int tid = threadIdx.x;
    int w = tid >> 6, lane = tid & 63, q = lane >> 4, x = lane & 15;
    int iw = i0 + w * 32;

    // stage the 256-row S-panel FIRST: 4096 lane-chunks, linear LDS dest
    #pragma unroll
    for (int it = 0; it < 16; ++it) {
        int l = tid + it * 256;
        GLL16(&g_Sb[b][j0 + (l >> 4)][(l & 15) * 8], &Sp[l * 8]);
    }

    // A-fragments (global, unswizzled) -- overlap the in-flight stage
    short8 af[2][4];
    #pragma unroll
    for (int m = 0; m < 2; ++m)
        #pragma unroll
        for (int kk = 0; kk < 4; ++kk)
            af[m][kk] = *(const short8*)&g_Tb[b][iw + m * 16 + x][(kk * 4 + q) * 8];

    // per-row aux (rows iw + m*16 + q*4 + v)
    float tq[8], rS[8], rC[8];
    #pragma unroll
    for (int m = 0; m < 2; ++m)
        #pragma unroll
        for (int v = 0; v < 4; ++v) {
            int row = iw + m * 16 + q * 4 + v;
            tq[m * 4 + v] = g_tsqr[b][row];
            rS[m * 4 + v] = (PASS >= 2) ? g_rowS[b][row] : 0.f;
            rC[m * 4 + v] = (PASS == 3) ? (C2L - g_rowLZ[b][row]) : 0.f;
        }

    // col aux for tile 0 (prefetch-1 pipeline)
    float sqc[4], cSc[4], cCc[4], sqn[4], cSn[4], cCn[4];
    #pragma unroll
    for (int n = 0; n < 4; ++n) {
        int col = j0 + n * 16 + x;
        sqn[n] = g_ssqr[b][col];
        cSn[n] = (PASS >= 2) ? g_colS[b][col] : 0.f;
        cCn[n] = (PASS == 3) ? (C2L - g_colLZ[b][col]) : 0.f;
    }

    float rstate[8];
    #pragma unroll
    for (int e = 0; e < 8; ++e)
        rstate[e] = (PASS == 1) ? 3.0e38f : (PASS == 2 ? 0.f : -3.0e38f);

    __syncthreads();   // single drain: stage + af + aux all landed

    for (int jt = 0; jt < 4; ++jt) {
        #pragma unroll
        for (int n = 0; n < 4; ++n) { sqc[n] = sqn[n]; cSc[n] = cSn[n]; cCc[n] = cCn[n]; }
        if (jt < 3) {
            #pragma unroll
            for (int n = 0; n < 4; ++n) {
                int col = j0 + (jt + 1) * 64 + n * 16 + x;
                sqn[n] = g_ssqr[b][col];
                if (PASS >= 2) cSn[n] = g_colS[b][col];
                if (PASS == 3) cCn[n] = C2L - g_colLZ[b][col];
            }
        }

        f32x4 acc[2][4];
        #pragma unroll
        for (int m = 0; m < 2; ++m)
            #pragma unroll
            for (int n = 0; n < 4; ++n)
                acc[m][n] = (f32x4){0.f, 0.f, 0.f, 0.f};

        #pragma unroll
        for (int kk = 0; kk < 4; ++kk) {
            short8 bf[4];
            #pragma unroll
            for (int n = 0; n < 4; ++n) {
                int r  = jt * 64 + n * 16 + x;
                int ch = (kk * 4 + q) ^ (r & 7);
                bf[n] = *(const short8*)&Sp[r * NC + ch * 8];
            }
            #pragma unroll
            for (int m = 0; m < 2; ++m)
                #pragma unroll
                for (int n = 0; n < 4; ++n)
                    acc[m][n] = __builtin_amdgcn_mfma_f32_16x16x32_bf16(af[m][kk], bf[n], acc[m][n], 0, 0, 0);
        }

        float cstate[4];
        #pragma unroll
        for (int n = 0; n < 4; ++n)
            cstate[n] = (PASS == 1) ? 3.0e38f : (PASS == 2 ? 0.f : -3.0e38f);

        #pragma unroll
        for (int m = 0; m < 2; ++m)
            #pragma unroll
            for (int n = 0; n < 4; ++n)
                #pragma unroll
                for (int v = 0; v < 4; ++v) {
                    float dv = fmaxf(fmaf(-2.f, acc[m][n][v], tq[m * 4 + v] + sqc[n]), 0.f);
                    if (PASS == 1) {
                        rstate[m * 4 + v] = fminf(rstate[m * 4 + v], dv);
                        cstate[n]         = fminf(cstate[n], dv);
                    } else if (PASS == 2) {
                        rstate[m * 4 + v] += fexp2(fmaf(dv, rS[m * 4 + v], C2L));
                        cstate[n]         += fexp2(fmaf(dv, cSc[n], C2L));
                    } else {
                        rstate[m * 4 + v] = fmaxf(rstate[m * 4 + v], fmaf(dv, cSc[n], cCc[n]));
                        cstate[n]         = fmaxf(cstate[n], fmaf(dv, rS[m * 4 + v], rC[m * 4 + v]));
                    }
                }

        // col partial: reduce over q-groups (rows within wave), exclusive store
        #pragma unroll
        for (int off = 16; off < 64; off <<= 1)
            #pragma unroll
            for (int n = 0; n < 4; ++n) {
                float o = __shfl_xor(cstate[n], off);
                cstate[n] = (PASS == 1) ? fminf(cstate[n], o)
                           : (PASS == 2) ? cstate[n] + o : fmaxf(cstate[n], o);
            }
        if (q == 0)
            #pragma unroll
            for (int n = 0; n < 4; ++n)
                g_colpart[b][st * 4 + w][j0 + jt * 64 + n * 16 + x] = cstate[n];
    }

    // row partial: reduce over 16 x-lanes, exclusive store (wave owns rows)
    #pragma unroll
    for (int off = 1; off < 16; off <<= 1)
        #pragma unroll
        for (int e = 0; e < 8; ++e) {
            float o = __shfl_xor(rstate[e], off);
            rstate[e] = (PASS == 1) ? fminf(rstate[e], o)
                       : (PASS == 2) ? rstate[e] + o : fmaxf(rstate[e], o);
        }
    if (x == 0)
        #pragma unroll
        for (int e = 0; e < 8; ++e)
            g_rowpart[b][pn][iw + (e >> 2) * 16 + q * 4 + (e & 3)] = rstate[e];
}

// Wide reduce: 512 blocks (2/CU), 16 els/block x 16 lane-parts.
// Col: 8 slots per part (depth 32 -> 8); row: 1 slot per part.
// lane = el*16 + part, so shfl_xor(1,2,4,8) combines parts within a wave.
template<int PASS>
__global__ void __launch_bounds__(256) reduce_kernel() {
    int bid = blockIdx.x;             // NB*256 = 512
    int b = bid >> 8, g = bid & 255;
    int tid = threadIdx.x;
    int el = g * 16 + (tid >> 4);
    int part = tid & 15;

    float ca = (PASS == 1) ? 3.0e38f : (PASS == 2 ? 0.f : -3.0e38f);
    #pragma unroll
    for (int k = 0; k < 8; ++k) {
        float cv = g_colpart[b][part * 8 + k][el];
        if (PASS == 1) ca = fminf(ca, cv);
        else if (PASS == 2) ca += cv;
        else ca = fmaxf(ca, cv);
    }
    float ra = g_rowpart[b][part][el];

    #pragma unroll
    for (int off = 1; off < 16; off <<= 1) {
        float co = __shfl_xor(ca, off), ro = __shfl_xor(ra, off);
        if (PASS == 1) { ca = fminf(ca, co); ra = fminf(ra, ro); }
        else if (PASS == 2) { ca += co; ra += ro; }
        else { ca = fmaxf(ca, co); ra = fmaxf(ra, ro); }
    }
    if (part == 0) {
        if (PASS == 1) { g_colS[b][el] = -(C2L / (ca + 1e-5f)); g_rowS[b][el] = -(C2L / (ra + 1e-5f)); }
        if (PASS == 2) { g_colLZ[b][el] = log2f(ca);            g_rowLZ[b][el] = log2f(ra); }
        if (PASS == 3) { g_colE[b][el] = fexp2(ca);             g_rowE[b][el] = fexp2(ra); }
    }
}

__global__ void final_kernel(float* __restrict__ out) {
    int tid = threadIdx.x;
    float s[4] = {0.f, 0.f, 0.f, 0.f};
    for (int i = tid; i < NN; i += 256) {
        s[0] += g_rowE[0][i];
        s[1] += g_rowE[1][i];
        s[2] += g_colE[0][i];
        s[3] += g_colE[1][i];
    }
    __shared__ float red[4][4];
    int lane = tid & 63, w = tid >> 6;
    #pragma unroll
    for (int t = 0; t < 4; ++t) {
        float v = s[t];
        #pragma unroll
        for (int off = 32; off; off >>= 1) v += __shfl_down(v, off);
        if (lane == 0) red[t][w] = v;
    }
    __syncthreads();
    if (tid == 0) {
        float o = 0.f;
        #pragma unroll
        for (int t = 0; t < 4; ++t) {
            float S = red[t][0] + red[t][1] + red[t][2] + red[t][3];
            o += logf(S);
        }
        out[0] = logf((float)NN) - 0.25f * o;
    }
}

extern "C" void kernel_launch(void* const* d_in, const int* in_sizes, int n_in,
                              void* d_out, int out_size, void* d_ws, size_t ws_size,
                              hipStream_t stream) {
    const float* src = (const float*)d_in[0];
    const float* tgt = (const float*)d_in[1];
    (void)in_sizes; (void)n_in; (void)d_ws; (void)ws_size; (void)out_size;

    transpose_prep<<<256, 256, 0, stream>>>(src, tgt);
    sweep_kernel<1><<<1024, 256, 0, stream>>>();
    reduce_kernel<1><<<512, 256, 0, stream>>>();
    sweep_kernel<2><<<1024, 256, 0, stream>>>();
    reduce_kernel<2><<<512, 256, 0, stream>>>();
    sweep_kernel<3><<<1024, 256, 0, stream>>>();
    reduce_kernel<3><<<512, 256, 0, stream>>>();
    final_kernel<<<1, 256, 0, stream>>>((float*)d_out);
}